// Round 1
// baseline (10.203 us; speedup 1.0000x reference)
//
#include <hip/hip_runtime.h>

// NEGLoss — key observation: the negative samples can NEVER land on a target
// index (their sampling distribution is exactly the freq distribution with all
// target indices masked to probability 0), and the loss only reads
// weights[target]. Hence weights[target] == pos_counts[target] and the whole
// jax.random.categorical / threefry machinery is provably irrelevant to the
// output:
//
//   loss = - sum_i c[t_i] * input[i, t_i]  /  sum_i c[t_i]
//   where c = histogram(target) over the vocab.
//
// Single block, 1024 threads. Histogram in LDS packed as 2 x uint16 per
// uint32 word (counts <= 4096 < 65536, no cross-half overflow possible):
// 25129 words ~= 98 KiB, fits the 160 KiB/CU LDS. LDS atomics keep everything
// workgroup-coherent (no global L1-staleness concerns), and d_ws is unused.

#define NEG_VOCAB 50257
#define NEG_HIST_WORDS ((NEG_VOCAB + 1) / 2)

__global__ __launch_bounds__(1024) void negloss_kernel(
    const float* __restrict__ input,   // [B, V] log-softmax, f32
    const int* __restrict__ target,    // [B] int32
    float* __restrict__ out,           // [1] f32
    int B, int V) {
    __shared__ unsigned int hist[NEG_HIST_WORDS];   // packed 2x u16 counts
    __shared__ float s_num[16];
    __shared__ float s_den[16];

    const int tid = threadIdx.x;
    const int T = blockDim.x;  // 1024

    // Phase 1: zero the histogram (re-zeroed every call -> deterministic).
    for (int v = tid; v < NEG_HIST_WORDS; v += T) hist[v] = 0u;
    __syncthreads();

    // Phase 2: histogram of target via LDS atomics.
    for (int i = tid; i < B; i += T) {
        int t = target[i];
        atomicAdd(&hist[t >> 1], 1u << ((t & 1) << 4));
    }
    __syncthreads();

    // Phase 3: gather input[i, t_i], weight by count, accumulate.
    float num = 0.f, den = 0.f;
    for (int i = tid; i < B; i += T) {
        int t = target[i];                       // L1/L2-hot reload
        unsigned int p = hist[t >> 1];
        float w = (float)((p >> ((t & 1) << 4)) & 0xFFFFu);
        float x = input[(long long)i * (long long)V + t];  // scattered HBM gather
        num += w * x;
        den += w;
    }

    // Wave-64 shuffle reduction.
#pragma unroll
    for (int off = 32; off > 0; off >>= 1) {
        num += __shfl_down(num, off, 64);
        den += __shfl_down(den, off, 64);
    }
    const int wave = tid >> 6;
    if ((tid & 63) == 0) { s_num[wave] = num; s_den[wave] = den; }
    __syncthreads();

    if (tid == 0) {
        float N = 0.f, D = 0.f;
        const int nw = T >> 6;
        for (int w = 0; w < nw; ++w) { N += s_num[w]; D += s_den[w]; }
        out[0] = -N / D;
    }
}

extern "C" void kernel_launch(void* const* d_in, const int* in_sizes, int n_in,
                              void* d_out, int out_size, void* d_ws, size_t ws_size,
                              hipStream_t stream) {
    const float* input = (const float*)d_in[0];   // [B, V]
    // d_in[1] (freqs) is provably unused by the output — see header comment.
    const int* target = (const int*)d_in[2];      // [B]
    float* out = (float*)d_out;

    const int V = in_sizes[1];   // 50257
    const int B = in_sizes[2];   // 4096

    negloss_kernel<<<dim3(1), dim3(1024), 0, stream>>>(input, target, out, B, V);
}